// Round 3
// baseline (1599.047 us; speedup 1.0000x reference)
//
#include <hip/hip_runtime.h>
#include <cstdint>
#include <cstddef>

#define HID 128
#define N_USERS 100000
#define N_JOBS  50000
#define N_EDGES 2000000
#define N_LABELS 500000

#define RBITS 7
#define RSIZE 128
#define NBJ ((N_JOBS  + RSIZE - 1) / RSIZE)   // 391
#define NBU ((N_USERS + RSIZE - 1) / RSIZE)   // 782

typedef __attribute__((ext_vector_type(8))) short short8;
typedef __attribute__((ext_vector_type(4))) float f32x4;

__device__ __forceinline__ unsigned short f2b(float f) {
    union { float f; unsigned u; } v; v.f = f;
    unsigned r = v.u + 0x7FFFu + ((v.u >> 16) & 1u);   // RNE to bf16
    return (unsigned short)(r >> 16);
}
__device__ __forceinline__ float b2f(unsigned h) {
    union { unsigned u; float f; } v; v.u = h << 16;
    return v.f;
}

// ---------------------------------------------------------------------------
// CSR build stage 1: bucket histogram (both sides), LDS-aggregated
// ---------------------------------------------------------------------------
__global__ __launch_bounds__(256) void bucket_hist(const int* __restrict__ src,
                                                   const int* __restrict__ dst,
                                                   int nE, int* __restrict__ bcnt_j,
                                                   int* __restrict__ bcnt_u) {
    __shared__ int hj[NBJ];
    __shared__ int hu[NBU];
    int t = threadIdx.x;
    for (int i = t; i < NBJ; i += 256) hj[i] = 0;
    for (int i = t; i < NBU; i += 256) hu[i] = 0;
    __syncthreads();
    int i = blockIdx.x * blockDim.x + t;
    int stride = gridDim.x * blockDim.x;
    for (; i < nE; i += stride) {
        atomicAdd(&hj[dst[i] >> RBITS], 1);
        atomicAdd(&hu[src[i] >> RBITS], 1);
    }
    __syncthreads();
    for (int i2 = t; i2 < NBJ; i2 += 256) if (hj[i2]) atomicAdd(&bcnt_j[i2], hj[i2]);
    for (int i2 = t; i2 < NBU; i2 += 256) if (hu[i2]) atomicAdd(&bcnt_u[i2], hu[i2]);
}

// ---------------------------------------------------------------------------
// CSR build stage 2: exclusive scan of bucket counts (one block per side)
// ---------------------------------------------------------------------------
__global__ __launch_bounds__(1024) void bucket_scan(int* __restrict__ bcnt_j, int* __restrict__ boff_j,
                                                    int* __restrict__ bcur_j,
                                                    int* __restrict__ bcnt_u, int* __restrict__ boff_u,
                                                    int* __restrict__ bcur_u) {
    int* bcnt = blockIdx.x ? bcnt_u : bcnt_j;
    int* boff = blockIdx.x ? boff_u : boff_j;
    int* bcur = blockIdx.x ? bcur_u : bcur_j;
    int n = blockIdx.x ? NBU : NBJ;
    __shared__ int sm[1024];
    int t = threadIdx.x;
    int v = (t < n) ? bcnt[t] : 0;
    sm[t] = v;
    __syncthreads();
    for (int d = 1; d < 1024; d <<= 1) {
        int q = (t >= d) ? sm[t - d] : 0;
        __syncthreads();
        sm[t] += q;
        __syncthreads();
    }
    if (t < n) { int e = sm[t] - v; boff[t] = e; bcur[t] = e; }
    if (t == 0) boff[n] = N_EDGES;
}

// ---------------------------------------------------------------------------
// CSR build stage 3: scatter (key,payload) pairs into bucket staging.
// Consecutive slots per bucket -> near-full-line writebacks.
// ---------------------------------------------------------------------------
__global__ void csr_pass1(const int* __restrict__ src, const int* __restrict__ dst,
                          int nE, int* __restrict__ bcur_j, int* __restrict__ bcur_u,
                          uint2* __restrict__ stage_j, uint2* __restrict__ stage_u) {
    int i = blockIdx.x * blockDim.x + threadIdx.x;
    int stride = gridDim.x * blockDim.x;
    for (; i < nE; i += stride) {
        int s = src[i], d = dst[i];
        int pj = atomicAdd(&bcur_j[d >> RBITS], 1);
        stage_j[pj] = make_uint2((unsigned)d, (unsigned)s);
        int pu = atomicAdd(&bcur_u[s >> RBITS], 1);
        stage_u[pu] = make_uint2((unsigned)s, (unsigned)d);
    }
}

// ---------------------------------------------------------------------------
// CSR build stage 4: per-bucket reorder. One workgroup owns one bucket
// (128 consecutive nodes); produces node off[] AND final vals[] with writes
// confined to the bucket's contiguous CSR window (== its staging window).
// Fused: blocks [0,NBJ) do the job side, [NBJ, NBJ+NBU) the user side.
// ---------------------------------------------------------------------------
__global__ __launch_bounds__(256) void csr_pass2(
    const uint2* __restrict__ stage_j, const int* __restrict__ boff_j,
    int* __restrict__ off_j, int* __restrict__ vals_j,
    const uint2* __restrict__ stage_u, const int* __restrict__ boff_u,
    int* __restrict__ off_u, int* __restrict__ vals_u) {
    __shared__ int cnt[RSIZE];
    __shared__ int sc[RSIZE];
    __shared__ int cur[RSIZE];
    int borig = blockIdx.x, t = threadIdx.x;
    const uint2* pairs; const int* boff; int* off; int* vals; int b; int nNodes;
    if (borig < NBJ) { pairs = stage_j; boff = boff_j; off = off_j; vals = vals_j; b = borig; nNodes = N_JOBS; }
    else             { pairs = stage_u; boff = boff_u; off = off_u; vals = vals_u; b = borig - NBJ; nNodes = N_USERS; }
    int node0 = b << RBITS;
    int sbeg = boff[b], send = boff[b + 1];
    if (t < RSIZE) cnt[t] = 0;
    __syncthreads();
    for (int e = sbeg + t; e < send; e += 256) {
        atomicAdd(&cnt[(int)pairs[e].x - node0], 1);
    }
    __syncthreads();
    int v = (t < RSIZE) ? cnt[t] : 0;
    if (t < RSIZE) sc[t] = v;
    __syncthreads();
    #pragma unroll
    for (int d = 1; d < RSIZE; d <<= 1) {
        int q = (t < RSIZE && t >= d) ? sc[t - d] : 0;
        __syncthreads();
        if (t < RSIZE) sc[t] += q;
        __syncthreads();
    }
    if (t < RSIZE) {
        int node = node0 + t;
        if (node < nNodes) {
            int base = sbeg + sc[t] - v;   // exclusive
            off[node] = base;
            cur[t] = base;
        }
    }
    __syncthreads();
    for (int e = sbeg + t; e < send; e += 256) {
        uint2 p = pairs[e];
        int slot = atomicAdd(&cur[(int)p.x - node0], 1);
        vals[slot] = (int)p.y;
    }
    if (t == 0 && borig == 0)   off_j[N_JOBS]  = N_EDGES;
    if (t == 0 && borig == NBJ) off_u[N_USERS] = N_EDGES;
}

// ---------------------------------------------------------------------------
// Mean aggregation over bf16 features: one wave per destination node
// ---------------------------------------------------------------------------
__global__ __launch_bounds__(256) void aggregate_bf16(const unsigned short* __restrict__ x,
                                                      const int* __restrict__ off,
                                                      const int* __restrict__ vals,
                                                      unsigned short* __restrict__ out, int nDst) {
    int node = blockIdx.x * 4 + (threadIdx.x >> 6);
    if (node >= nDst) return;
    int lane = threadIdx.x & 63;
    int beg = off[node], end = off[node + 1];
    float a0 = 0.f, a1 = 0.f;
    int e = beg;
    for (; e + 1 < end; e += 2) {
        int s0 = vals[e], s1 = vals[e + 1];
        unsigned v0 = *reinterpret_cast<const unsigned*>(x + (size_t)s0 * HID + lane * 2);
        unsigned v1 = *reinterpret_cast<const unsigned*>(x + (size_t)s1 * HID + lane * 2);
        a0 += b2f(v0 & 0xffffu) + b2f(v1 & 0xffffu);
        a1 += b2f(v0 >> 16) + b2f(v1 >> 16);
    }
    if (e < end) {
        unsigned v0 = *reinterpret_cast<const unsigned*>(x + (size_t)vals[e] * HID + lane * 2);
        a0 += b2f(v0 & 0xffffu);
        a1 += b2f(v0 >> 16);
    }
    float inv = 1.0f / fmaxf((float)(end - beg), 1.0f);
    unsigned r = (unsigned)f2b(a0 * inv) | ((unsigned)f2b(a1 * inv) << 16);
    *reinterpret_cast<unsigned*>(out + (size_t)node * HID + lane * 2) = r;
}

// ---------------------------------------------------------------------------
// Encoder: out_bf16 = relu(BN(X @ W^T + b)).  X:[M,K] fp32, W:[128,K] fp32.
// 128x128 tile, BK=64 bf16, MFMA 16x16x32, XOR-swizzled LDS.
// ---------------------------------------------------------------------------
__global__ __launch_bounds__(256) void encoder_mfma(
    const float* __restrict__ X, const float* __restrict__ W,
    const float* __restrict__ bias, const float* __restrict__ gamma,
    const float* __restrict__ beta, const float* __restrict__ mean,
    const float* __restrict__ var, unsigned short* __restrict__ out, int M, int K) {
    __shared__ char lds[32768];              // A: [0,16K), B: [16K,32K)
    int tid = threadIdx.x;
    int m0 = blockIdx.x * 128;
    int wid = tid >> 6, lane = tid & 63;
    int wr = wid >> 1, wc = wid & 1;
    int lrow = lane & 15, lgrp = lane >> 4;
    f32x4 acc[4][4];
    #pragma unroll
    for (int m = 0; m < 4; ++m)
        #pragma unroll
        for (int n = 0; n < 4; ++n) acc[m][n] = (f32x4){0.f, 0.f, 0.f, 0.f};

    for (int k0 = 0; k0 < K; k0 += 64) {
        #pragma unroll
        for (int i = 0; i < 8; ++i) {        // A tile: 2048 float4, 8/thread
            int f = tid + i * 256;
            int row = f >> 4, fi = f & 15;
            int gr = m0 + row;
            float4 v = make_float4(0.f, 0.f, 0.f, 0.f);
            if (gr < M) v = *reinterpret_cast<const float4*>(X + (size_t)gr * K + k0 + fi * 4);
            unsigned lo = (unsigned)f2b(v.x) | ((unsigned)f2b(v.y) << 16);
            unsigned hi = (unsigned)f2b(v.z) | ((unsigned)f2b(v.w) << 16);
            int slot = fi >> 1, rest = (fi & 1) * 8;
            int o = row * 128 + (((slot ^ (row & 7)) << 4) | rest);
            *reinterpret_cast<uint2*>(lds + o) = make_uint2(lo, hi);
        }
        #pragma unroll
        for (int i = 0; i < 8; ++i) {        // W tile
            int f = tid + i * 256;
            int row = f >> 4, fi = f & 15;
            float4 v = *reinterpret_cast<const float4*>(W + (size_t)row * K + k0 + fi * 4);
            unsigned lo = (unsigned)f2b(v.x) | ((unsigned)f2b(v.y) << 16);
            unsigned hi = (unsigned)f2b(v.z) | ((unsigned)f2b(v.w) << 16);
            int slot = fi >> 1, rest = (fi & 1) * 8;
            int o = 16384 + row * 128 + (((slot ^ (row & 7)) << 4) | rest);
            *reinterpret_cast<uint2*>(lds + o) = make_uint2(lo, hi);
        }
        __syncthreads();
        #pragma unroll
        for (int ks = 0; ks < 2; ++ks) {
            short8 af[4], bf[4];
            #pragma unroll
            for (int m = 0; m < 4; ++m) {
                int row = wr * 64 + m * 16 + lrow;
                int slot = ks * 4 + lgrp;
                af[m] = *reinterpret_cast<const short8*>(lds + row * 128 + ((slot ^ (row & 7)) << 4));
            }
            #pragma unroll
            for (int n = 0; n < 4; ++n) {
                int row = wc * 64 + n * 16 + lrow;
                int slot = ks * 4 + lgrp;
                bf[n] = *reinterpret_cast<const short8*>(lds + 16384 + row * 128 + ((slot ^ (row & 7)) << 4));
            }
            #pragma unroll
            for (int m = 0; m < 4; ++m)
                #pragma unroll
                for (int n = 0; n < 4; ++n)
                    acc[m][n] = __builtin_amdgcn_mfma_f32_16x16x32_bf16(af[m], bf[n], acc[m][n], 0, 0, 0);
        }
        __syncthreads();
    }
    float sc[4], sh[4]; int col[4];
    #pragma unroll
    for (int n = 0; n < 4; ++n) {
        int gc = wc * 64 + n * 16 + lrow;
        col[n] = gc;
        float s = gamma[gc] * rsqrtf(var[gc] + 1e-5f);
        sc[n] = s;
        sh[n] = (bias[gc] - mean[gc]) * s + beta[gc];
    }
    #pragma unroll
    for (int m = 0; m < 4; ++m)
        #pragma unroll
        for (int j = 0; j < 4; ++j) {
            int row = m0 + wr * 64 + m * 16 + lgrp * 4 + j;
            if (row < M) {
                #pragma unroll
                for (int n = 0; n < 4; ++n) {
                    float v = fmaxf(acc[m][n][j] * sc[n] + sh[n], 0.f);
                    out[(size_t)row * HID + col[n]] = f2b(v);
                }
            }
        }
}

// ---------------------------------------------------------------------------
// SAGE dual GEMM: out = [relu](Aagg @ WA^T + bl + Bx @ WB^T)
// Aagg,Bx: [M,128] bf16. WA,WB: [128,128] fp32. out bf16 or fp32.
// ---------------------------------------------------------------------------
__global__ __launch_bounds__(256) void sage_mfma(
    const unsigned short* __restrict__ Aagg, const unsigned short* __restrict__ Bx,
    const float* __restrict__ WA, const float* __restrict__ WB,
    const float* __restrict__ bl, void* __restrict__ outv,
    int M, int doRelu, int outF32) {
    __shared__ char lds[32768];
    int tid = threadIdx.x;
    int m0 = blockIdx.x * 128;
    int wid = tid >> 6, lane = tid & 63;
    int wr = wid >> 1, wc = wid & 1;
    int lrow = lane & 15, lgrp = lane >> 4;
    f32x4 acc[4][4];
    #pragma unroll
    for (int m = 0; m < 4; ++m)
        #pragma unroll
        for (int n = 0; n < 4; ++n) acc[m][n] = (f32x4){0.f, 0.f, 0.f, 0.f};

    for (int s = 0; s < 4; ++s) {
        const unsigned short* src = (s < 2) ? Aagg : Bx;
        const float* Wp = (s < 2) ? WA : WB;
        int k0 = (s & 1) * 64;
        #pragma unroll
        for (int i = 0; i < 4; ++i) {        // A tile: bf16 source
            int u = tid + i * 256;
            int row = u >> 3, slot = u & 7;
            int gr = m0 + row;
            uint4 v = make_uint4(0, 0, 0, 0);
            if (gr < M) v = *reinterpret_cast<const uint4*>(src + (size_t)gr * HID + k0 + slot * 8);
            *reinterpret_cast<uint4*>(lds + row * 128 + ((slot ^ (row & 7)) << 4)) = v;
        }
        #pragma unroll
        for (int i = 0; i < 8; ++i) {        // W tile: fp32 -> bf16
            int f = tid + i * 256;
            int row = f >> 4, fi = f & 15;
            float4 v = *reinterpret_cast<const float4*>(Wp + (size_t)row * HID + k0 + fi * 4);
            unsigned lo = (unsigned)f2b(v.x) | ((unsigned)f2b(v.y) << 16);
            unsigned hi = (unsigned)f2b(v.z) | ((unsigned)f2b(v.w) << 16);
            int slot = fi >> 1, rest = (fi & 1) * 8;
            int o = 16384 + row * 128 + (((slot ^ (row & 7)) << 4) | rest);
            *reinterpret_cast<uint2*>(lds + o) = make_uint2(lo, hi);
        }
        __syncthreads();
        #pragma unroll
        for (int ks = 0; ks < 2; ++ks) {
            short8 af[4], bf[4];
            #pragma unroll
            for (int m = 0; m < 4; ++m) {
                int row = wr * 64 + m * 16 + lrow;
                int slot = ks * 4 + lgrp;
                af[m] = *reinterpret_cast<const short8*>(lds + row * 128 + ((slot ^ (row & 7)) << 4));
            }
            #pragma unroll
            for (int n = 0; n < 4; ++n) {
                int row = wc * 64 + n * 16 + lrow;
                int slot = ks * 4 + lgrp;
                bf[n] = *reinterpret_cast<const short8*>(lds + 16384 + row * 128 + ((slot ^ (row & 7)) << 4));
            }
            #pragma unroll
            for (int m = 0; m < 4; ++m)
                #pragma unroll
                for (int n = 0; n < 4; ++n)
                    acc[m][n] = __builtin_amdgcn_mfma_f32_16x16x32_bf16(af[m], bf[n], acc[m][n], 0, 0, 0);
        }
        __syncthreads();
    }
    float blv[4]; int col[4];
    #pragma unroll
    for (int n = 0; n < 4; ++n) { col[n] = wc * 64 + n * 16 + lrow; blv[n] = bl[col[n]]; }
    #pragma unroll
    for (int m = 0; m < 4; ++m)
        #pragma unroll
        for (int j = 0; j < 4; ++j) {
            int row = m0 + wr * 64 + m * 16 + lgrp * 4 + j;
            if (row < M) {
                #pragma unroll
                for (int n = 0; n < 4; ++n) {
                    float v = acc[m][n][j] + blv[n];
                    if (doRelu) v = fmaxf(v, 0.f);
                    if (outF32) ((float*)outv)[(size_t)row * HID + col[n]] = v;
                    else        ((unsigned short*)outv)[(size_t)row * HID + col[n]] = f2b(v);
                }
            }
        }
}

// ---------------------------------------------------------------------------
// Link readout: one wave per label edge, fp32 inputs
// ---------------------------------------------------------------------------
__global__ __launch_bounds__(256) void dot_kernel(const float* __restrict__ U,
                                                  const float* __restrict__ J,
                                                  const int* __restrict__ ls,
                                                  const int* __restrict__ ld,
                                                  float* __restrict__ out, int nL) {
    int w = (int)((blockIdx.x * blockDim.x + threadIdx.x) >> 6);
    int lane = threadIdx.x & 63;
    if (w >= nL) return;
    int a = ls[w], c = ld[w];
    float2 uv = *reinterpret_cast<const float2*>(U + (size_t)a * HID + lane * 2);
    float2 jv = *reinterpret_cast<const float2*>(J + (size_t)c * HID + lane * 2);
    float p = uv.x * jv.x + uv.y * jv.y;
    #pragma unroll
    for (int s = 32; s > 0; s >>= 1) p += __shfl_xor(p, s, 64);
    if (lane == 0) out[w] = p;
}

// ---------------------------------------------------------------------------
extern "C" void kernel_launch(void* const* d_in, const int* in_sizes, int n_in,
                              void* d_out, int out_size, void* d_ws, size_t ws_size,
                              hipStream_t stream) {
    const float* user_x     = (const float*)d_in[0];
    const float* job_x      = (const float*)d_in[1];
    const float* user_W     = (const float*)d_in[2];
    const float* user_b     = (const float*)d_in[3];
    const float* user_gamma = (const float*)d_in[4];
    const float* user_beta  = (const float*)d_in[5];
    const float* user_mean  = (const float*)d_in[6];
    const float* user_var   = (const float*)d_in[7];
    const float* job_W      = (const float*)d_in[8];
    const float* job_b      = (const float*)d_in[9];
    const float* job_gamma  = (const float*)d_in[10];
    const float* job_beta   = (const float*)d_in[11];
    const float* job_mean   = (const float*)d_in[12];
    const float* job_var    = (const float*)d_in[13];
    const float* l1_rates_Wl = (const float*)d_in[14];
    const float* l1_rates_Wr = (const float*)d_in[15];
    const float* l1_rev_Wl   = (const float*)d_in[16];
    const float* l1_rev_Wr   = (const float*)d_in[17];
    const float* l2_rates_Wl = (const float*)d_in[18];
    const float* l2_rates_Wr = (const float*)d_in[19];
    const float* l2_rev_Wl   = (const float*)d_in[20];
    const float* l2_rev_Wr   = (const float*)d_in[21];
    const float* l1_rates_bl = (const float*)d_in[22];
    const float* l1_rev_bl   = (const float*)d_in[23];
    const float* l2_rates_bl = (const float*)d_in[24];
    const float* l2_rev_bl   = (const float*)d_in[25];
    const int* rates_src = (const int*)d_in[26];
    const int* rates_dst = (const int*)d_in[27];
    const int* label_src = (const int*)d_in[28];
    const int* label_dst = (const int*)d_in[29];

    // ---- workspace layout ----
    char* ws = (char*)d_ws;
    size_t o = 0;
    auto alloc = [&](size_t bytes) -> void* {
        void* p = ws + o;
        o = (o + bytes + 511) & ~(size_t)511;
        return p;
    };
    unsigned short* u_bf = (unsigned short*)alloc((size_t)N_USERS * HID * 2);
    unsigned short* j_bf = (unsigned short*)alloc((size_t)N_JOBS  * HID * 2);
    unsigned short* u1   = (unsigned short*)alloc((size_t)N_USERS * HID * 2);
    unsigned short* j1   = (unsigned short*)alloc((size_t)N_JOBS  * HID * 2);
    unsigned short* aggU = (unsigned short*)alloc((size_t)N_USERS * HID * 2);
    unsigned short* aggJ = (unsigned short*)alloc((size_t)N_JOBS  * HID * 2);
    float* u2f = (float*)alloc((size_t)N_USERS * HID * 4);
    float* j2f = (float*)alloc((size_t)N_JOBS  * HID * 4);
    int* vals_j = (int*)alloc((size_t)N_EDGES * 4);
    int* vals_u = (int*)alloc((size_t)N_EDGES * 4);
    uint2* stage_j = (uint2*)alloc((size_t)N_EDGES * 8);
    uint2* stage_u = (uint2*)alloc((size_t)N_EDGES * 8);
    int* off_j  = (int*)alloc((size_t)(N_JOBS + 1) * 4);
    int* off_u  = (int*)alloc((size_t)(N_USERS + 1) * 4);
    int* bcnt_j = (int*)alloc((size_t)(NBJ + 1) * 4);
    int* bcnt_u = (int*)alloc((size_t)(NBU + 1) * 4);
    int* boff_j = (int*)alloc((size_t)(NBJ + 1) * 4);
    int* boff_u = (int*)alloc((size_t)(NBU + 1) * 4);
    int* bcur_j = (int*)alloc((size_t)(NBJ + 1) * 4);
    int* bcur_u = (int*)alloc((size_t)(NBU + 1) * 4);
    (void)ws_size; (void)n_in; (void)in_sizes; (void)out_size;

    // ---- CSR build (binned, shared by both layers) ----
    hipMemsetAsync(bcnt_j, 0, (size_t)(NBJ + 1) * 4, stream);
    hipMemsetAsync(bcnt_u, 0, (size_t)(NBU + 1) * 4, stream);
    bucket_hist<<<512, 256, 0, stream>>>(rates_src, rates_dst, N_EDGES, bcnt_j, bcnt_u);
    bucket_scan<<<2, 1024, 0, stream>>>(bcnt_j, boff_j, bcur_j, bcnt_u, boff_u, bcur_u);
    csr_pass1<<<2048, 256, 0, stream>>>(rates_src, rates_dst, N_EDGES,
                                        bcur_j, bcur_u, stage_j, stage_u);
    csr_pass2<<<NBJ + NBU, 256, 0, stream>>>(stage_j, boff_j, off_j, vals_j,
                                             stage_u, boff_u, off_u, vals_u);

    // ---- encoders (bf16 MFMA) ----
    encoder_mfma<<<(N_USERS + 127) / 128, 256, 0, stream>>>(
        user_x, user_W, user_b, user_gamma, user_beta, user_mean, user_var, u_bf, N_USERS, 512);
    encoder_mfma<<<(N_JOBS + 127) / 128, 256, 0, stream>>>(
        job_x, job_W, job_b, job_gamma, job_beta, job_mean, job_var, j_bf, N_JOBS, 768);

    // ---- SAGE layer 1 (bf16 out, relu) ----
    aggregate_bf16<<<(N_JOBS + 3) / 4, 256, 0, stream>>>(u_bf, off_j, vals_j, aggJ, N_JOBS);
    sage_mfma<<<(N_JOBS + 127) / 128, 256, 0, stream>>>(
        aggJ, j_bf, l1_rates_Wl, l1_rates_Wr, l1_rates_bl, (void*)j1, N_JOBS, 1, 0);
    aggregate_bf16<<<(N_USERS + 3) / 4, 256, 0, stream>>>(j_bf, off_u, vals_u, aggU, N_USERS);
    sage_mfma<<<(N_USERS + 127) / 128, 256, 0, stream>>>(
        aggU, u_bf, l1_rev_Wl, l1_rev_Wr, l1_rev_bl, (void*)u1, N_USERS, 1, 0);

    // ---- SAGE layer 2 (fp32 out, no relu) ----
    aggregate_bf16<<<(N_JOBS + 3) / 4, 256, 0, stream>>>(u1, off_j, vals_j, aggJ, N_JOBS);
    sage_mfma<<<(N_JOBS + 127) / 128, 256, 0, stream>>>(
        aggJ, j1, l2_rates_Wl, l2_rates_Wr, l2_rates_bl, (void*)j2f, N_JOBS, 0, 1);
    aggregate_bf16<<<(N_USERS + 3) / 4, 256, 0, stream>>>(j1, off_u, vals_u, aggU, N_USERS);
    sage_mfma<<<(N_USERS + 127) / 128, 256, 0, stream>>>(
        aggU, u1, l2_rev_Wl, l2_rev_Wr, l2_rev_bl, (void*)u2f, N_USERS, 0, 1);

    // ---- link readout ----
    dot_kernel<<<(N_LABELS * 64 + 255) / 256, 256, 0, stream>>>(
        u2f, j2f, label_src, label_dst, (float*)d_out, N_LABELS);
}

// Round 4
// 938.487 us; speedup vs baseline: 1.7039x; 1.7039x over previous
//
#include <hip/hip_runtime.h>
#include <cstdint>
#include <cstddef>

#define HID 128
#define N_USERS 100000
#define N_JOBS  50000
#define N_EDGES 2000000
#define N_LABELS 500000

#define RBITS 8
#define RSIZE 256
#define NBJ ((N_JOBS  + RSIZE - 1) / RSIZE)   // 196
#define NBU ((N_USERS + RSIZE - 1) / RSIZE)   // 391
#define P1CHUNK 8192

typedef __attribute__((ext_vector_type(8))) short short8;
typedef __attribute__((ext_vector_type(4))) float f32x4;

__device__ __forceinline__ unsigned short f2b(float f) {
    union { float f; unsigned u; } v; v.f = f;
    unsigned r = v.u + 0x7FFFu + ((v.u >> 16) & 1u);   // RNE to bf16
    return (unsigned short)(r >> 16);
}
__device__ __forceinline__ float b2f(unsigned h) {
    union { unsigned u; float f; } v; v.u = h << 16;
    return v.f;
}

// ---------------------------------------------------------------------------
// CSR build stage 1: bucket histogram (both sides), LDS-aggregated
// ---------------------------------------------------------------------------
__global__ __launch_bounds__(256) void bucket_hist(const int* __restrict__ src,
                                                   const int* __restrict__ dst,
                                                   int nE, int* __restrict__ bcnt_j,
                                                   int* __restrict__ bcnt_u) {
    __shared__ int hj[NBJ];
    __shared__ int hu[NBU];
    int t = threadIdx.x;
    for (int i = t; i < NBJ; i += 256) hj[i] = 0;
    for (int i = t; i < NBU; i += 256) hu[i] = 0;
    __syncthreads();
    int i = blockIdx.x * blockDim.x + t;
    int stride = gridDim.x * blockDim.x;
    for (; i < nE; i += stride) {
        atomicAdd(&hj[dst[i] >> RBITS], 1);
        atomicAdd(&hu[src[i] >> RBITS], 1);
    }
    __syncthreads();
    for (int i2 = t; i2 < NBJ; i2 += 256) if (hj[i2]) atomicAdd(&bcnt_j[i2], hj[i2]);
    for (int i2 = t; i2 < NBU; i2 += 256) if (hu[i2]) atomicAdd(&bcnt_u[i2], hu[i2]);
}

// ---------------------------------------------------------------------------
// CSR build stage 2: exclusive scan of bucket counts (one block per side)
// ---------------------------------------------------------------------------
__global__ __launch_bounds__(1024) void bucket_scan(int* __restrict__ bcnt_j, int* __restrict__ boff_j,
                                                    int* __restrict__ bcur_j,
                                                    int* __restrict__ bcnt_u, int* __restrict__ boff_u,
                                                    int* __restrict__ bcur_u) {
    int* bcnt = blockIdx.x ? bcnt_u : bcnt_j;
    int* boff = blockIdx.x ? boff_u : boff_j;
    int* bcur = blockIdx.x ? bcur_u : bcur_j;
    int n = blockIdx.x ? NBU : NBJ;
    __shared__ int sm[1024];
    int t = threadIdx.x;
    int v = (t < n) ? bcnt[t] : 0;
    sm[t] = v;
    __syncthreads();
    for (int d = 1; d < 1024; d <<= 1) {
        int q = (t >= d) ? sm[t - d] : 0;
        __syncthreads();
        sm[t] += q;
        __syncthreads();
    }
    if (t < n) { int e = sm[t] - v; boff[t] = e; bcur[t] = e; }
    if (t == 0) boff[n] = N_EDGES;
}

// ---------------------------------------------------------------------------
// CSR build stage 3: LDS-binned radix partition. Each block owns a contiguous
// chunk of edges; counts buckets in LDS, bulk-reserves global runs (1 atomic
// per (block,bucket)), then scatters packed words (local_key<<24 | payload)
// into its contiguous per-bucket runs.
// ---------------------------------------------------------------------------
__global__ __launch_bounds__(256) void csr_pass1(const int* __restrict__ src,
                                                 const int* __restrict__ dst,
                                                 int nE, int* __restrict__ gcur_j,
                                                 int* __restrict__ gcur_u,
                                                 unsigned* __restrict__ stage_j,
                                                 unsigned* __restrict__ stage_u) {
    __shared__ int cur_j[NBJ];
    __shared__ int cur_u[NBU];
    int t = threadIdx.x;
    int e0 = blockIdx.x * P1CHUNK;
    int e1 = min(e0 + P1CHUNK, nE);
    for (int i = t; i < NBJ; i += 256) cur_j[i] = 0;
    for (int i = t; i < NBU; i += 256) cur_u[i] = 0;
    __syncthreads();
    // phase 1: local count
    for (int e = e0 + t; e < e1; e += 256) {
        atomicAdd(&cur_j[dst[e] >> RBITS], 1);
        atomicAdd(&cur_u[src[e] >> RBITS], 1);
    }
    __syncthreads();
    // phase 2: bulk-reserve global runs; cur becomes the run base
    for (int i = t; i < NBJ; i += 256) {
        int c = cur_j[i];
        cur_j[i] = c ? atomicAdd(&gcur_j[i], c) : 0;
    }
    for (int i = t; i < NBU; i += 256) {
        int c = cur_u[i];
        cur_u[i] = c ? atomicAdd(&gcur_u[i], c) : 0;
    }
    __syncthreads();
    // phase 3: scatter into contiguous runs
    for (int e = e0 + t; e < e1; e += 256) {
        int d = dst[e], s = src[e];
        int pj = atomicAdd(&cur_j[d >> RBITS], 1);
        stage_j[pj] = ((unsigned)(d & (RSIZE - 1)) << 24) | (unsigned)s;
        int pu = atomicAdd(&cur_u[s >> RBITS], 1);
        stage_u[pu] = ((unsigned)(s & (RSIZE - 1)) << 24) | (unsigned)d;
    }
}

// ---------------------------------------------------------------------------
// CSR build stage 4: per-bucket reorder (256 nodes/bucket). Produces node
// off[] and final vals[], writes confined to the bucket's CSR window.
// Blocks [0,NBJ) = job side, [NBJ, NBJ+NBU) = user side.
// ---------------------------------------------------------------------------
__global__ __launch_bounds__(256) void csr_pass2(
    const unsigned* __restrict__ stage_j, const int* __restrict__ boff_j,
    int* __restrict__ off_j, int* __restrict__ vals_j,
    const unsigned* __restrict__ stage_u, const int* __restrict__ boff_u,
    int* __restrict__ off_u, int* __restrict__ vals_u) {
    __shared__ int cnt[RSIZE];
    __shared__ int sc[RSIZE];
    __shared__ int cur[RSIZE];
    int borig = blockIdx.x, t = threadIdx.x;
    const unsigned* words; const int* boff; int* off; int* vals; int b; int nNodes;
    if (borig < NBJ) { words = stage_j; boff = boff_j; off = off_j; vals = vals_j; b = borig; nNodes = N_JOBS; }
    else             { words = stage_u; boff = boff_u; off = off_u; vals = vals_u; b = borig - NBJ; nNodes = N_USERS; }
    int node0 = b << RBITS;
    int sbeg = boff[b], send = boff[b + 1];
    cnt[t] = 0;
    __syncthreads();
    for (int e = sbeg + t; e < send; e += 256) {
        atomicAdd(&cnt[words[e] >> 24], 1);
    }
    __syncthreads();
    int v = cnt[t];
    sc[t] = v;
    __syncthreads();
    #pragma unroll
    for (int d = 1; d < RSIZE; d <<= 1) {
        int q = (t >= d) ? sc[t - d] : 0;
        __syncthreads();
        sc[t] += q;
        __syncthreads();
    }
    int node = node0 + t;
    if (node < nNodes) {
        int base = sbeg + sc[t] - v;   // exclusive
        off[node] = base;
        cur[t] = base;
    }
    __syncthreads();
    for (int e = sbeg + t; e < send; e += 256) {
        unsigned w = words[e];
        int slot = atomicAdd(&cur[w >> 24], 1);
        vals[slot] = (int)(w & 0xFFFFFFu);
    }
    if (t == 0 && borig == 0)   off_j[N_JOBS]  = N_EDGES;
    if (t == 0 && borig == NBJ) off_u[N_USERS] = N_EDGES;
}

// ---------------------------------------------------------------------------
// Mean aggregation over bf16 features: one wave per destination node
// ---------------------------------------------------------------------------
__global__ __launch_bounds__(256) void aggregate_bf16(const unsigned short* __restrict__ x,
                                                      const int* __restrict__ off,
                                                      const int* __restrict__ vals,
                                                      unsigned short* __restrict__ out, int nDst) {
    int node = blockIdx.x * 4 + (threadIdx.x >> 6);
    if (node >= nDst) return;
    int lane = threadIdx.x & 63;
    int beg = off[node], end = off[node + 1];
    float a0 = 0.f, a1 = 0.f;
    int e = beg;
    for (; e + 1 < end; e += 2) {
        int s0 = vals[e], s1 = vals[e + 1];
        unsigned v0 = *reinterpret_cast<const unsigned*>(x + (size_t)s0 * HID + lane * 2);
        unsigned v1 = *reinterpret_cast<const unsigned*>(x + (size_t)s1 * HID + lane * 2);
        a0 += b2f(v0 & 0xffffu) + b2f(v1 & 0xffffu);
        a1 += b2f(v0 >> 16) + b2f(v1 >> 16);
    }
    if (e < end) {
        unsigned v0 = *reinterpret_cast<const unsigned*>(x + (size_t)vals[e] * HID + lane * 2);
        a0 += b2f(v0 & 0xffffu);
        a1 += b2f(v0 >> 16);
    }
    float inv = 1.0f / fmaxf((float)(end - beg), 1.0f);
    unsigned r = (unsigned)f2b(a0 * inv) | ((unsigned)f2b(a1 * inv) << 16);
    *reinterpret_cast<unsigned*>(out + (size_t)node * HID + lane * 2) = r;
}

// ---------------------------------------------------------------------------
// Encoder: out_bf16 = relu(BN(X @ W^T + b)).  X:[M,K] fp32, W:[128,K] fp32.
// 128x128 tile, BK=64 bf16, MFMA 16x16x32, XOR-swizzled LDS.
// ---------------------------------------------------------------------------
__global__ __launch_bounds__(256) void encoder_mfma(
    const float* __restrict__ X, const float* __restrict__ W,
    const float* __restrict__ bias, const float* __restrict__ gamma,
    const float* __restrict__ beta, const float* __restrict__ mean,
    const float* __restrict__ var, unsigned short* __restrict__ out, int M, int K) {
    __shared__ char lds[32768];              // A: [0,16K), B: [16K,32K)
    int tid = threadIdx.x;
    int m0 = blockIdx.x * 128;
    int wid = tid >> 6, lane = tid & 63;
    int wr = wid >> 1, wc = wid & 1;
    int lrow = lane & 15, lgrp = lane >> 4;
    f32x4 acc[4][4];
    #pragma unroll
    for (int m = 0; m < 4; ++m)
        #pragma unroll
        for (int n = 0; n < 4; ++n) acc[m][n] = (f32x4){0.f, 0.f, 0.f, 0.f};

    for (int k0 = 0; k0 < K; k0 += 64) {
        #pragma unroll
        for (int i = 0; i < 8; ++i) {        // A tile: 2048 float4, 8/thread
            int f = tid + i * 256;
            int row = f >> 4, fi = f & 15;
            int gr = m0 + row;
            float4 v = make_float4(0.f, 0.f, 0.f, 0.f);
            if (gr < M) v = *reinterpret_cast<const float4*>(X + (size_t)gr * K + k0 + fi * 4);
            unsigned lo = (unsigned)f2b(v.x) | ((unsigned)f2b(v.y) << 16);
            unsigned hi = (unsigned)f2b(v.z) | ((unsigned)f2b(v.w) << 16);
            int slot = fi >> 1, rest = (fi & 1) * 8;
            int o = row * 128 + (((slot ^ (row & 7)) << 4) | rest);
            *reinterpret_cast<uint2*>(lds + o) = make_uint2(lo, hi);
        }
        #pragma unroll
        for (int i = 0; i < 8; ++i) {        // W tile
            int f = tid + i * 256;
            int row = f >> 4, fi = f & 15;
            float4 v = *reinterpret_cast<const float4*>(W + (size_t)row * K + k0 + fi * 4);
            unsigned lo = (unsigned)f2b(v.x) | ((unsigned)f2b(v.y) << 16);
            unsigned hi = (unsigned)f2b(v.z) | ((unsigned)f2b(v.w) << 16);
            int slot = fi >> 1, rest = (fi & 1) * 8;
            int o = 16384 + row * 128 + (((slot ^ (row & 7)) << 4) | rest);
            *reinterpret_cast<uint2*>(lds + o) = make_uint2(lo, hi);
        }
        __syncthreads();
        #pragma unroll
        for (int ks = 0; ks < 2; ++ks) {
            short8 af[4], bf[4];
            #pragma unroll
            for (int m = 0; m < 4; ++m) {
                int row = wr * 64 + m * 16 + lrow;
                int slot = ks * 4 + lgrp;
                af[m] = *reinterpret_cast<const short8*>(lds + row * 128 + ((slot ^ (row & 7)) << 4));
            }
            #pragma unroll
            for (int n = 0; n < 4; ++n) {
                int row = wc * 64 + n * 16 + lrow;
                int slot = ks * 4 + lgrp;
                bf[n] = *reinterpret_cast<const short8*>(lds + 16384 + row * 128 + ((slot ^ (row & 7)) << 4));
            }
            #pragma unroll
            for (int m = 0; m < 4; ++m)
                #pragma unroll
                for (int n = 0; n < 4; ++n)
                    acc[m][n] = __builtin_amdgcn_mfma_f32_16x16x32_bf16(af[m], bf[n], acc[m][n], 0, 0, 0);
        }
        __syncthreads();
    }
    float sc[4], sh[4]; int col[4];
    #pragma unroll
    for (int n = 0; n < 4; ++n) {
        int gc = wc * 64 + n * 16 + lrow;
        col[n] = gc;
        float s = gamma[gc] * rsqrtf(var[gc] + 1e-5f);
        sc[n] = s;
        sh[n] = (bias[gc] - mean[gc]) * s + beta[gc];
    }
    #pragma unroll
    for (int m = 0; m < 4; ++m)
        #pragma unroll
        for (int j = 0; j < 4; ++j) {
            int row = m0 + wr * 64 + m * 16 + lgrp * 4 + j;
            if (row < M) {
                #pragma unroll
                for (int n = 0; n < 4; ++n) {
                    float v = fmaxf(acc[m][n][j] * sc[n] + sh[n], 0.f);
                    out[(size_t)row * HID + col[n]] = f2b(v);
                }
            }
        }
}

// ---------------------------------------------------------------------------
// SAGE dual GEMM: out = [relu](Aagg @ WA^T + bl + Bx @ WB^T)
// Aagg,Bx: [M,128] bf16. WA,WB: [128,128] fp32. out bf16 or fp32.
// ---------------------------------------------------------------------------
__global__ __launch_bounds__(256) void sage_mfma(
    const unsigned short* __restrict__ Aagg, const unsigned short* __restrict__ Bx,
    const float* __restrict__ WA, const float* __restrict__ WB,
    const float* __restrict__ bl, void* __restrict__ outv,
    int M, int doRelu, int outF32) {
    __shared__ char lds[32768];
    int tid = threadIdx.x;
    int m0 = blockIdx.x * 128;
    int wid = tid >> 6, lane = tid & 63;
    int wr = wid >> 1, wc = wid & 1;
    int lrow = lane & 15, lgrp = lane >> 4;
    f32x4 acc[4][4];
    #pragma unroll
    for (int m = 0; m < 4; ++m)
        #pragma unroll
        for (int n = 0; n < 4; ++n) acc[m][n] = (f32x4){0.f, 0.f, 0.f, 0.f};

    for (int s = 0; s < 4; ++s) {
        const unsigned short* src = (s < 2) ? Aagg : Bx;
        const float* Wp = (s < 2) ? WA : WB;
        int k0 = (s & 1) * 64;
        #pragma unroll
        for (int i = 0; i < 4; ++i) {        // A tile: bf16 source
            int u = tid + i * 256;
            int row = u >> 3, slot = u & 7;
            int gr = m0 + row;
            uint4 v = make_uint4(0, 0, 0, 0);
            if (gr < M) v = *reinterpret_cast<const uint4*>(src + (size_t)gr * HID + k0 + slot * 8);
            *reinterpret_cast<uint4*>(lds + row * 128 + ((slot ^ (row & 7)) << 4)) = v;
        }
        #pragma unroll
        for (int i = 0; i < 8; ++i) {        // W tile: fp32 -> bf16
            int f = tid + i * 256;
            int row = f >> 4, fi = f & 15;
            float4 v = *reinterpret_cast<const float4*>(Wp + (size_t)row * HID + k0 + fi * 4);
            unsigned lo = (unsigned)f2b(v.x) | ((unsigned)f2b(v.y) << 16);
            unsigned hi = (unsigned)f2b(v.z) | ((unsigned)f2b(v.w) << 16);
            int slot = fi >> 1, rest = (fi & 1) * 8;
            int o = 16384 + row * 128 + (((slot ^ (row & 7)) << 4) | rest);
            *reinterpret_cast<uint2*>(lds + o) = make_uint2(lo, hi);
        }
        __syncthreads();
        #pragma unroll
        for (int ks = 0; ks < 2; ++ks) {
            short8 af[4], bf[4];
            #pragma unroll
            for (int m = 0; m < 4; ++m) {
                int row = wr * 64 + m * 16 + lrow;
                int slot = ks * 4 + lgrp;
                af[m] = *reinterpret_cast<const short8*>(lds + row * 128 + ((slot ^ (row & 7)) << 4));
            }
            #pragma unroll
            for (int n = 0; n < 4; ++n) {
                int row = wc * 64 + n * 16 + lrow;
                int slot = ks * 4 + lgrp;
                bf[n] = *reinterpret_cast<const short8*>(lds + 16384 + row * 128 + ((slot ^ (row & 7)) << 4));
            }
            #pragma unroll
            for (int m = 0; m < 4; ++m)
                #pragma unroll
                for (int n = 0; n < 4; ++n)
                    acc[m][n] = __builtin_amdgcn_mfma_f32_16x16x32_bf16(af[m], bf[n], acc[m][n], 0, 0, 0);
        }
        __syncthreads();
    }
    float blv[4]; int col[4];
    #pragma unroll
    for (int n = 0; n < 4; ++n) { col[n] = wc * 64 + n * 16 + lrow; blv[n] = bl[col[n]]; }
    #pragma unroll
    for (int m = 0; m < 4; ++m)
        #pragma unroll
        for (int j = 0; j < 4; ++j) {
            int row = m0 + wr * 64 + m * 16 + lgrp * 4 + j;
            if (row < M) {
                #pragma unroll
                for (int n = 0; n < 4; ++n) {
                    float v = acc[m][n][j] + blv[n];
                    if (doRelu) v = fmaxf(v, 0.f);
                    if (outF32) ((float*)outv)[(size_t)row * HID + col[n]] = v;
                    else        ((unsigned short*)outv)[(size_t)row * HID + col[n]] = f2b(v);
                }
            }
        }
}

// ---------------------------------------------------------------------------
// Link readout: one wave per label edge, fp32 inputs
// ---------------------------------------------------------------------------
__global__ __launch_bounds__(256) void dot_kernel(const float* __restrict__ U,
                                                  const float* __restrict__ J,
                                                  const int* __restrict__ ls,
                                                  const int* __restrict__ ld,
                                                  float* __restrict__ out, int nL) {
    int w = (int)((blockIdx.x * blockDim.x + threadIdx.x) >> 6);
    int lane = threadIdx.x & 63;
    if (w >= nL) return;
    int a = ls[w], c = ld[w];
    float2 uv = *reinterpret_cast<const float2*>(U + (size_t)a * HID + lane * 2);
    float2 jv = *reinterpret_cast<const float2*>(J + (size_t)c * HID + lane * 2);
    float p = uv.x * jv.x + uv.y * jv.y;
    #pragma unroll
    for (int s = 32; s > 0; s >>= 1) p += __shfl_xor(p, s, 64);
    if (lane == 0) out[w] = p;
}

// ---------------------------------------------------------------------------
extern "C" void kernel_launch(void* const* d_in, const int* in_sizes, int n_in,
                              void* d_out, int out_size, void* d_ws, size_t ws_size,
                              hipStream_t stream) {
    const float* user_x     = (const float*)d_in[0];
    const float* job_x      = (const float*)d_in[1];
    const float* user_W     = (const float*)d_in[2];
    const float* user_b     = (const float*)d_in[3];
    const float* user_gamma = (const float*)d_in[4];
    const float* user_beta  = (const float*)d_in[5];
    const float* user_mean  = (const float*)d_in[6];
    const float* user_var   = (const float*)d_in[7];
    const float* job_W      = (const float*)d_in[8];
    const float* job_b      = (const float*)d_in[9];
    const float* job_gamma  = (const float*)d_in[10];
    const float* job_beta   = (const float*)d_in[11];
    const float* job_mean   = (const float*)d_in[12];
    const float* job_var    = (const float*)d_in[13];
    const float* l1_rates_Wl = (const float*)d_in[14];
    const float* l1_rates_Wr = (const float*)d_in[15];
    const float* l1_rev_Wl   = (const float*)d_in[16];
    const float* l1_rev_Wr   = (const float*)d_in[17];
    const float* l2_rates_Wl = (const float*)d_in[18];
    const float* l2_rates_Wr = (const float*)d_in[19];
    const float* l2_rev_Wl   = (const float*)d_in[20];
    const float* l2_rev_Wr   = (const float*)d_in[21];
    const float* l1_rates_bl = (const float*)d_in[22];
    const float* l1_rev_bl   = (const float*)d_in[23];
    const float* l2_rates_bl = (const float*)d_in[24];
    const float* l2_rev_bl   = (const float*)d_in[25];
    const int* rates_src = (const int*)d_in[26];
    const int* rates_dst = (const int*)d_in[27];
    const int* label_src = (const int*)d_in[28];
    const int* label_dst = (const int*)d_in[29];

    // ---- workspace layout ----
    char* ws = (char*)d_ws;
    size_t o = 0;
    auto alloc = [&](size_t bytes) -> void* {
        void* p = ws + o;
        o = (o + bytes + 511) & ~(size_t)511;
        return p;
    };
    unsigned short* u_bf = (unsigned short*)alloc((size_t)N_USERS * HID * 2);
    unsigned short* j_bf = (unsigned short*)alloc((size_t)N_JOBS  * HID * 2);
    unsigned short* u1   = (unsigned short*)alloc((size_t)N_USERS * HID * 2);
    unsigned short* j1   = (unsigned short*)alloc((size_t)N_JOBS  * HID * 2);
    unsigned short* aggU = (unsigned short*)alloc((size_t)N_USERS * HID * 2);
    unsigned short* aggJ = (unsigned short*)alloc((size_t)N_JOBS  * HID * 2);
    float* u2f = (float*)alloc((size_t)N_USERS * HID * 4);
    float* j2f = (float*)alloc((size_t)N_JOBS  * HID * 4);
    int* vals_j = (int*)alloc((size_t)N_EDGES * 4);
    int* vals_u = (int*)alloc((size_t)N_EDGES * 4);
    unsigned* stage_j = (unsigned*)alloc((size_t)N_EDGES * 4);
    unsigned* stage_u = (unsigned*)alloc((size_t)N_EDGES * 4);
    int* off_j  = (int*)alloc((size_t)(N_JOBS + 1) * 4);
    int* off_u  = (int*)alloc((size_t)(N_USERS + 1) * 4);
    int* bcnt_j = (int*)alloc((size_t)(NBJ + 1) * 4);
    int* bcnt_u = (int*)alloc((size_t)(NBU + 1) * 4);
    int* boff_j = (int*)alloc((size_t)(NBJ + 1) * 4);
    int* boff_u = (int*)alloc((size_t)(NBU + 1) * 4);
    int* bcur_j = (int*)alloc((size_t)(NBJ + 1) * 4);
    int* bcur_u = (int*)alloc((size_t)(NBU + 1) * 4);
    (void)ws_size; (void)n_in; (void)in_sizes; (void)out_size;

    // ---- CSR build (binned, shared by both layers) ----
    hipMemsetAsync(bcnt_j, 0, (size_t)(NBJ + 1) * 4, stream);
    hipMemsetAsync(bcnt_u, 0, (size_t)(NBU + 1) * 4, stream);
    bucket_hist<<<512, 256, 0, stream>>>(rates_src, rates_dst, N_EDGES, bcnt_j, bcnt_u);
    bucket_scan<<<2, 1024, 0, stream>>>(bcnt_j, boff_j, bcur_j, bcnt_u, boff_u, bcur_u);
    csr_pass1<<<(N_EDGES + P1CHUNK - 1) / P1CHUNK, 256, 0, stream>>>(
        rates_src, rates_dst, N_EDGES, bcur_j, bcur_u, stage_j, stage_u);
    csr_pass2<<<NBJ + NBU, 256, 0, stream>>>(stage_j, boff_j, off_j, vals_j,
                                             stage_u, boff_u, off_u, vals_u);

    // ---- encoders (bf16 MFMA) ----
    encoder_mfma<<<(N_USERS + 127) / 128, 256, 0, stream>>>(
        user_x, user_W, user_b, user_gamma, user_beta, user_mean, user_var, u_bf, N_USERS, 512);
    encoder_mfma<<<(N_JOBS + 127) / 128, 256, 0, stream>>>(
        job_x, job_W, job_b, job_gamma, job_beta, job_mean, job_var, j_bf, N_JOBS, 768);

    // ---- SAGE layer 1 (bf16 out, relu) ----
    aggregate_bf16<<<(N_JOBS + 3) / 4, 256, 0, stream>>>(u_bf, off_j, vals_j, aggJ, N_JOBS);
    sage_mfma<<<(N_JOBS + 127) / 128, 256, 0, stream>>>(
        aggJ, j_bf, l1_rates_Wl, l1_rates_Wr, l1_rates_bl, (void*)j1, N_JOBS, 1, 0);
    aggregate_bf16<<<(N_USERS + 3) / 4, 256, 0, stream>>>(j_bf, off_u, vals_u, aggU, N_USERS);
    sage_mfma<<<(N_USERS + 127) / 128, 256, 0, stream>>>(
        aggU, u_bf, l1_rev_Wl, l1_rev_Wr, l1_rev_bl, (void*)u1, N_USERS, 1, 0);

    // ---- SAGE layer 2 (fp32 out, no relu) ----
    aggregate_bf16<<<(N_JOBS + 3) / 4, 256, 0, stream>>>(u1, off_j, vals_j, aggJ, N_JOBS);
    sage_mfma<<<(N_JOBS + 127) / 128, 256, 0, stream>>>(
        aggJ, j1, l2_rates_Wl, l2_rates_Wr, l2_rates_bl, (void*)j2f, N_JOBS, 0, 1);
    aggregate_bf16<<<(N_USERS + 3) / 4, 256, 0, stream>>>(j1, off_u, vals_u, aggU, N_USERS);
    sage_mfma<<<(N_USERS + 127) / 128, 256, 0, stream>>>(
        aggU, u1, l2_rev_Wl, l2_rev_Wr, l2_rev_bl, (void*)u2f, N_USERS, 0, 1);

    // ---- link readout ----
    dot_kernel<<<(N_LABELS * 64 + 255) / 256, 256, 0, stream>>>(
        u2f, j2f, label_src, label_dst, (float*)d_out, N_LABELS);
}

// Round 5
// 821.330 us; speedup vs baseline: 1.9469x; 1.1426x over previous
//
#include <hip/hip_runtime.h>
#include <cstdint>
#include <cstddef>

#define HID 128
#define N_USERS 100000
#define N_JOBS  50000
#define N_EDGES 2000000
#define N_LABELS 500000

#define RBITS 8
#define RSIZE 256
#define NBJ ((N_JOBS  + RSIZE - 1) / RSIZE)   // 196
#define NBU ((N_USERS + RSIZE - 1) / RSIZE)   // 391
#define P1CHUNK 8192

typedef __attribute__((ext_vector_type(8))) short short8;
typedef __attribute__((ext_vector_type(4))) float f32x4;

__device__ __forceinline__ unsigned short f2b(float f) {
    union { float f; unsigned u; } v; v.f = f;
    unsigned r = v.u + 0x7FFFu + ((v.u >> 16) & 1u);   // RNE to bf16
    return (unsigned short)(r >> 16);
}
__device__ __forceinline__ float b2f(unsigned h) {
    union { unsigned u; float f; } v; v.u = h << 16;
    return v.f;
}

// ---------------------------------------------------------------------------
// One-shot: convert all 10 weight matrices fp32 -> bf16 into ws.
// Layout (bf16 elems): [0,65536) user_W, [65536,163840) job_W,
// [163840 + k*16384) for k = l1rWl,l1rWr,l1vWl,l1vWr,l2rWl,l2rWr,l2vWl,l2vWr
// ---------------------------------------------------------------------------
__global__ __launch_bounds__(256) void cvt_weights(
    const float* __restrict__ uW, const float* __restrict__ jW,
    const float* __restrict__ a, const float* __restrict__ b,
    const float* __restrict__ c, const float* __restrict__ d,
    const float* __restrict__ e, const float* __restrict__ f,
    const float* __restrict__ g, const float* __restrict__ h,
    unsigned short* __restrict__ ow) {
    int i4 = blockIdx.x * 256 + threadIdx.x;   // float4 index
    if (i4 >= 73728) return;                    // 294912 floats total
    int i = i4 * 4;
    const float* src; int base;
    if (i < 65536)       { src = uW; base = 0; }
    else if (i < 163840) { src = jW; base = 65536; }
    else {
        int k = (i - 163840) >> 14;
        const float* s4 = (k < 4) ? ((k < 2) ? (k == 0 ? a : b) : (k == 2 ? c : d))
                                  : ((k < 6) ? (k == 4 ? e : f) : (k == 6 ? g : h));
        src = s4; base = 163840 + (k << 14);
    }
    float4 v = *reinterpret_cast<const float4*>(src + (i - base));
    unsigned lo = (unsigned)f2b(v.x) | ((unsigned)f2b(v.y) << 16);
    unsigned hi = (unsigned)f2b(v.z) | ((unsigned)f2b(v.w) << 16);
    *reinterpret_cast<uint2*>(ow + i) = make_uint2(lo, hi);
}

// ---------------------------------------------------------------------------
// CSR build stage 1: bucket histogram (both sides), LDS-aggregated
// ---------------------------------------------------------------------------
__global__ __launch_bounds__(256) void bucket_hist(const int* __restrict__ src,
                                                   const int* __restrict__ dst,
                                                   int nE, int* __restrict__ bcnt_j,
                                                   int* __restrict__ bcnt_u) {
    __shared__ int hj[NBJ];
    __shared__ int hu[NBU];
    int t = threadIdx.x;
    for (int i = t; i < NBJ; i += 256) hj[i] = 0;
    for (int i = t; i < NBU; i += 256) hu[i] = 0;
    __syncthreads();
    int i = blockIdx.x * blockDim.x + t;
    int stride = gridDim.x * blockDim.x;
    for (; i < nE; i += stride) {
        atomicAdd(&hj[dst[i] >> RBITS], 1);
        atomicAdd(&hu[src[i] >> RBITS], 1);
    }
    __syncthreads();
    for (int i2 = t; i2 < NBJ; i2 += 256) if (hj[i2]) atomicAdd(&bcnt_j[i2], hj[i2]);
    for (int i2 = t; i2 < NBU; i2 += 256) if (hu[i2]) atomicAdd(&bcnt_u[i2], hu[i2]);
}

// ---------------------------------------------------------------------------
// CSR build stage 2: exclusive scan of bucket counts (one block per side)
// ---------------------------------------------------------------------------
__global__ __launch_bounds__(1024) void bucket_scan(int* __restrict__ bcnt_j, int* __restrict__ boff_j,
                                                    int* __restrict__ bcur_j,
                                                    int* __restrict__ bcnt_u, int* __restrict__ boff_u,
                                                    int* __restrict__ bcur_u) {
    int* bcnt = blockIdx.x ? bcnt_u : bcnt_j;
    int* boff = blockIdx.x ? boff_u : boff_j;
    int* bcur = blockIdx.x ? bcur_u : bcur_j;
    int n = blockIdx.x ? NBU : NBJ;
    __shared__ int sm[1024];
    int t = threadIdx.x;
    int v = (t < n) ? bcnt[t] : 0;
    sm[t] = v;
    __syncthreads();
    for (int d = 1; d < 1024; d <<= 1) {
        int q = (t >= d) ? sm[t - d] : 0;
        __syncthreads();
        sm[t] += q;
        __syncthreads();
    }
    if (t < n) { int e = sm[t] - v; boff[t] = e; bcur[t] = e; }
    if (t == 0) boff[n] = N_EDGES;
}

// ---------------------------------------------------------------------------
// CSR build stage 3: LDS-binned radix partition (bulk-reserved runs)
// ---------------------------------------------------------------------------
__global__ __launch_bounds__(256) void csr_pass1(const int* __restrict__ src,
                                                 const int* __restrict__ dst,
                                                 int nE, int* __restrict__ gcur_j,
                                                 int* __restrict__ gcur_u,
                                                 unsigned* __restrict__ stage_j,
                                                 unsigned* __restrict__ stage_u) {
    __shared__ int cur_j[NBJ];
    __shared__ int cur_u[NBU];
    int t = threadIdx.x;
    int e0 = blockIdx.x * P1CHUNK;
    int e1 = min(e0 + P1CHUNK, nE);
    for (int i = t; i < NBJ; i += 256) cur_j[i] = 0;
    for (int i = t; i < NBU; i += 256) cur_u[i] = 0;
    __syncthreads();
    for (int e = e0 + t; e < e1; e += 256) {
        atomicAdd(&cur_j[dst[e] >> RBITS], 1);
        atomicAdd(&cur_u[src[e] >> RBITS], 1);
    }
    __syncthreads();
    for (int i = t; i < NBJ; i += 256) {
        int c = cur_j[i];
        cur_j[i] = c ? atomicAdd(&gcur_j[i], c) : 0;
    }
    for (int i = t; i < NBU; i += 256) {
        int c = cur_u[i];
        cur_u[i] = c ? atomicAdd(&gcur_u[i], c) : 0;
    }
    __syncthreads();
    for (int e = e0 + t; e < e1; e += 256) {
        int d = dst[e], s = src[e];
        int pj = atomicAdd(&cur_j[d >> RBITS], 1);
        stage_j[pj] = ((unsigned)(d & (RSIZE - 1)) << 24) | (unsigned)s;
        int pu = atomicAdd(&cur_u[s >> RBITS], 1);
        stage_u[pu] = ((unsigned)(s & (RSIZE - 1)) << 24) | (unsigned)d;
    }
}

// ---------------------------------------------------------------------------
// CSR build stage 4: per-bucket reorder (256 nodes/bucket)
// ---------------------------------------------------------------------------
__global__ __launch_bounds__(256) void csr_pass2(
    const unsigned* __restrict__ stage_j, const int* __restrict__ boff_j,
    int* __restrict__ off_j, int* __restrict__ vals_j,
    const unsigned* __restrict__ stage_u, const int* __restrict__ boff_u,
    int* __restrict__ off_u, int* __restrict__ vals_u) {
    __shared__ int cnt[RSIZE];
    __shared__ int sc[RSIZE];
    __shared__ int cur[RSIZE];
    int borig = blockIdx.x, t = threadIdx.x;
    const unsigned* words; const int* boff; int* off; int* vals; int b; int nNodes;
    if (borig < NBJ) { words = stage_j; boff = boff_j; off = off_j; vals = vals_j; b = borig; nNodes = N_JOBS; }
    else             { words = stage_u; boff = boff_u; off = off_u; vals = vals_u; b = borig - NBJ; nNodes = N_USERS; }
    int node0 = b << RBITS;
    int sbeg = boff[b], send = boff[b + 1];
    cnt[t] = 0;
    __syncthreads();
    for (int e = sbeg + t; e < send; e += 256) {
        atomicAdd(&cnt[words[e] >> 24], 1);
    }
    __syncthreads();
    int v = cnt[t];
    sc[t] = v;
    __syncthreads();
    #pragma unroll
    for (int d = 1; d < RSIZE; d <<= 1) {
        int q = (t >= d) ? sc[t - d] : 0;
        __syncthreads();
        sc[t] += q;
        __syncthreads();
    }
    int node = node0 + t;
    if (node < nNodes) {
        int base = sbeg + sc[t] - v;   // exclusive
        off[node] = base;
        cur[t] = base;
    }
    __syncthreads();
    for (int e = sbeg + t; e < send; e += 256) {
        unsigned w = words[e];
        int slot = atomicAdd(&cur[w >> 24], 1);
        vals[slot] = (int)(w & 0xFFFFFFu);
    }
    if (t == 0 && borig == 0)   off_j[N_JOBS]  = N_EDGES;
    if (t == 0 && borig == NBJ) off_u[N_USERS] = N_EDGES;
}

// ---------------------------------------------------------------------------
// Mean aggregation over bf16 features: one wave per destination node,
// 4-edge unroll for gather ILP
// ---------------------------------------------------------------------------
__global__ __launch_bounds__(256) void aggregate_bf16(const unsigned short* __restrict__ x,
                                                      const int* __restrict__ off,
                                                      const int* __restrict__ vals,
                                                      unsigned short* __restrict__ out, int nDst) {
    int node = blockIdx.x * 4 + (threadIdx.x >> 6);
    if (node >= nDst) return;
    int lane = threadIdx.x & 63;
    int beg = off[node], end = off[node + 1];
    float a0 = 0.f, a1 = 0.f;
    int e = beg;
    for (; e + 3 < end; e += 4) {
        int s0 = vals[e], s1 = vals[e + 1], s2 = vals[e + 2], s3 = vals[e + 3];
        unsigned v0 = *reinterpret_cast<const unsigned*>(x + (size_t)s0 * HID + lane * 2);
        unsigned v1 = *reinterpret_cast<const unsigned*>(x + (size_t)s1 * HID + lane * 2);
        unsigned v2 = *reinterpret_cast<const unsigned*>(x + (size_t)s2 * HID + lane * 2);
        unsigned v3 = *reinterpret_cast<const unsigned*>(x + (size_t)s3 * HID + lane * 2);
        a0 += b2f(v0 & 0xffffu) + b2f(v1 & 0xffffu) + b2f(v2 & 0xffffu) + b2f(v3 & 0xffffu);
        a1 += b2f(v0 >> 16) + b2f(v1 >> 16) + b2f(v2 >> 16) + b2f(v3 >> 16);
    }
    for (; e < end; ++e) {
        unsigned v0 = *reinterpret_cast<const unsigned*>(x + (size_t)vals[e] * HID + lane * 2);
        a0 += b2f(v0 & 0xffffu);
        a1 += b2f(v0 >> 16);
    }
    float inv = 1.0f / fmaxf((float)(end - beg), 1.0f);
    unsigned r = (unsigned)f2b(a0 * inv) | ((unsigned)f2b(a1 * inv) << 16);
    *reinterpret_cast<unsigned*>(out + (size_t)node * HID + lane * 2) = r;
}

// ---------------------------------------------------------------------------
// Encoder: out_bf16 = relu(BN(X @ W^T + b)).  X:[M,K] fp32, Wb:[128,K] bf16.
// 64x128 tile, BK=64, 4 waves (each 64x32), reg-prefetch pipeline.
// ---------------------------------------------------------------------------
__global__ __launch_bounds__(256) void encoder_mfma(
    const float* __restrict__ X, const unsigned short* __restrict__ Wb,
    const float* __restrict__ bias, const float* __restrict__ gamma,
    const float* __restrict__ beta, const float* __restrict__ mean,
    const float* __restrict__ var, unsigned short* __restrict__ out, int M, int K) {
    __shared__ char lds[24576];              // A: [0,8K), W: [8K,24K)
    int tid = threadIdx.x;
    int m0 = blockIdx.x * 64;
    int w = tid >> 6, lane = tid & 63;
    int lrow = lane & 15, lgrp = lane >> 4;
    f32x4 acc[4][2];
    #pragma unroll
    for (int m = 0; m < 4; ++m)
        #pragma unroll
        for (int n = 0; n < 2; ++n) acc[m][n] = (f32x4){0.f, 0.f, 0.f, 0.f};

    int fi = tid & 15;                       // X staging: float4 col
    int xr = tid >> 4;                       // X staging: row base (+=16)
    int ws8 = tid & 7;                       // W staging: 16B slot
    int wr8 = tid >> 3;                      // W staging: row base (+=32)

    float4 rx[4];
    uint4  rw[4];
    auto LOADT = [&](int k0) {
        #pragma unroll
        for (int i = 0; i < 4; ++i) {
            int gr = m0 + xr + i * 16;
            rx[i] = make_float4(0.f, 0.f, 0.f, 0.f);
            if (gr < M) rx[i] = *reinterpret_cast<const float4*>(X + (size_t)gr * K + k0 + fi * 4);
        }
        #pragma unroll
        for (int i = 0; i < 4; ++i) {
            int row = wr8 + i * 32;
            rw[i] = *reinterpret_cast<const uint4*>(Wb + (size_t)row * K + k0 + ws8 * 8);
        }
    };
    auto STORET = [&]() {
        int slot = fi >> 1, rest = (fi & 1) * 8;
        #pragma unroll
        for (int i = 0; i < 4; ++i) {
            int row = xr + i * 16;
            unsigned lo = (unsigned)f2b(rx[i].x) | ((unsigned)f2b(rx[i].y) << 16);
            unsigned hi = (unsigned)f2b(rx[i].z) | ((unsigned)f2b(rx[i].w) << 16);
            *reinterpret_cast<uint2*>(lds + row * 128 + (((slot ^ (row & 7)) << 4) | rest)) = make_uint2(lo, hi);
        }
        #pragma unroll
        for (int i = 0; i < 4; ++i) {
            int row = wr8 + i * 32;
            *reinterpret_cast<uint4*>(lds + 8192 + row * 128 + ((ws8 ^ (row & 7)) << 4)) = rw[i];
        }
    };

    int nt = K >> 6;
    LOADT(0);
    for (int t = 0; t < nt; ++t) {
        STORET();
        __syncthreads();
        if (t + 1 < nt) LOADT((t + 1) << 6);
        #pragma unroll
        for (int ks = 0; ks < 2; ++ks) {
            short8 af[4], bf[2];
            int slot = ks * 4 + lgrp;
            #pragma unroll
            for (int m = 0; m < 4; ++m) {
                int row = m * 16 + lrow;
                af[m] = *reinterpret_cast<const short8*>(lds + row * 128 + ((slot ^ (row & 7)) << 4));
            }
            #pragma unroll
            for (int n = 0; n < 2; ++n) {
                int row = w * 32 + n * 16 + lrow;
                bf[n] = *reinterpret_cast<const short8*>(lds + 8192 + row * 128 + ((slot ^ (row & 7)) << 4));
            }
            #pragma unroll
            for (int m = 0; m < 4; ++m)
                #pragma unroll
                for (int n = 0; n < 2; ++n)
                    acc[m][n] = __builtin_amdgcn_mfma_f32_16x16x32_bf16(af[m], bf[n], acc[m][n], 0, 0, 0);
        }
        __syncthreads();
    }
    float sc[2], sh[2]; int col[2];
    #pragma unroll
    for (int n = 0; n < 2; ++n) {
        int gc = w * 32 + n * 16 + lrow;
        col[n] = gc;
        float s = gamma[gc] * rsqrtf(var[gc] + 1e-5f);
        sc[n] = s;
        sh[n] = (bias[gc] - mean[gc]) * s + beta[gc];
    }
    #pragma unroll
    for (int m = 0; m < 4; ++m)
        #pragma unroll
        for (int j = 0; j < 4; ++j) {
            int row = m0 + m * 16 + lgrp * 4 + j;
            if (row < M) {
                #pragma unroll
                for (int n = 0; n < 2; ++n) {
                    float v = fmaxf(acc[m][n][j] * sc[n] + sh[n], 0.f);
                    out[(size_t)row * HID + col[n]] = f2b(v);
                }
            }
        }
}

// ---------------------------------------------------------------------------
// SAGE dual GEMM: out = [relu](Aagg @ WA^T + bl + Bx @ WB^T)
// Aagg,Bx:[M,128] bf16; WA,WB:[128,128] bf16. 64x128 tile, reg-prefetch.
// ---------------------------------------------------------------------------
__global__ __launch_bounds__(256) void sage_mfma(
    const unsigned short* __restrict__ Aagg, const unsigned short* __restrict__ Bx,
    const unsigned short* __restrict__ WA, const unsigned short* __restrict__ WB,
    const float* __restrict__ bl, void* __restrict__ outv,
    int M, int doRelu, int outF32) {
    __shared__ char lds[24576];
    int tid = threadIdx.x;
    int m0 = blockIdx.x * 64;
    int w = tid >> 6, lane = tid & 63;
    int lrow = lane & 15, lgrp = lane >> 4;
    f32x4 acc[4][2];
    #pragma unroll
    for (int m = 0; m < 4; ++m)
        #pragma unroll
        for (int n = 0; n < 2; ++n) acc[m][n] = (f32x4){0.f, 0.f, 0.f, 0.f};

    int as8 = tid & 7;                        // 16B slot index
    int ar8 = tid >> 3;                       // row base (+=32)

    uint4 ra[2], rw[4];
    auto LOADT = [&](int s) {
        const unsigned short* srcp = (s < 2) ? Aagg : Bx;
        const unsigned short* Wp = (s < 2) ? WA : WB;
        int k0 = (s & 1) * 64;
        #pragma unroll
        for (int i = 0; i < 2; ++i) {
            int gr = m0 + ar8 + i * 32;
            ra[i] = make_uint4(0, 0, 0, 0);
            if (gr < M) ra[i] = *reinterpret_cast<const uint4*>(srcp + (size_t)gr * HID + k0 + as8 * 8);
        }
        #pragma unroll
        for (int i = 0; i < 4; ++i) {
            int row = ar8 + i * 32;
            rw[i] = *reinterpret_cast<const uint4*>(Wp + (size_t)row * HID + k0 + as8 * 8);
        }
    };
    auto STORET = [&]() {
        #pragma unroll
        for (int i = 0; i < 2; ++i) {
            int row = ar8 + i * 32;
            *reinterpret_cast<uint4*>(lds + row * 128 + ((as8 ^ (row & 7)) << 4)) = ra[i];
        }
        #pragma unroll
        for (int i = 0; i < 4; ++i) {
            int row = ar8 + i * 32;
            *reinterpret_cast<uint4*>(lds + 8192 + row * 128 + ((as8 ^ (row & 7)) << 4)) = rw[i];
        }
    };

    LOADT(0);
    #pragma unroll
    for (int s = 0; s < 4; ++s) {
        STORET();
        __syncthreads();
        if (s < 3) LOADT(s + 1);
        #pragma unroll
        for (int ks = 0; ks < 2; ++ks) {
            short8 af[4], bf[2];
            int slot = ks * 4 + lgrp;
            #pragma unroll
            for (int m = 0; m < 4; ++m) {
                int row = m * 16 + lrow;
                af[m] = *reinterpret_cast<const short8*>(lds + row * 128 + ((slot ^ (row & 7)) << 4));
            }
            #pragma unroll
            for (int n = 0; n < 2; ++n) {
                int row = w * 32 + n * 16 + lrow;
                bf[n] = *reinterpret_cast<const short8*>(lds + 8192 + row * 128 + ((slot ^ (row & 7)) << 4));
            }
            #pragma unroll
            for (int m = 0; m < 4; ++m)
                #pragma unroll
                for (int n = 0; n < 2; ++n)
                    acc[m][n] = __builtin_amdgcn_mfma_f32_16x16x32_bf16(af[m], bf[n], acc[m][n], 0, 0, 0);
        }
        __syncthreads();
    }
    float blv[2]; int col[2];
    #pragma unroll
    for (int n = 0; n < 2; ++n) { col[n] = w * 32 + n * 16 + lrow; blv[n] = bl[col[n]]; }
    #pragma unroll
    for (int m = 0; m < 4; ++m)
        #pragma unroll
        for (int j = 0; j < 4; ++j) {
            int row = m0 + m * 16 + lgrp * 4 + j;
            if (row < M) {
                #pragma unroll
                for (int n = 0; n < 2; ++n) {
                    float v = acc[m][n][j] + blv[n];
                    if (doRelu) v = fmaxf(v, 0.f);
                    if (outF32) ((float*)outv)[(size_t)row * HID + col[n]] = v;
                    else        ((unsigned short*)outv)[(size_t)row * HID + col[n]] = f2b(v);
                }
            }
        }
}

// ---------------------------------------------------------------------------
// Link readout: 32 lanes per label edge (2 edges/wave), float4 loads
// ---------------------------------------------------------------------------
__global__ __launch_bounds__(256) void dot_kernel(const float* __restrict__ U,
                                                  const float* __restrict__ J,
                                                  const int* __restrict__ ls,
                                                  const int* __restrict__ ld,
                                                  float* __restrict__ out, int nL) {
    int gw = (int)((blockIdx.x * blockDim.x + threadIdx.x) >> 5);
    int l = threadIdx.x & 31;
    if (gw >= nL) return;
    int a = ls[gw], c = ld[gw];
    float4 uv = *reinterpret_cast<const float4*>(U + (size_t)a * HID + l * 4);
    float4 jv = *reinterpret_cast<const float4*>(J + (size_t)c * HID + l * 4);
    float p = uv.x * jv.x + uv.y * jv.y + uv.z * jv.z + uv.w * jv.w;
    #pragma unroll
    for (int s = 16; s > 0; s >>= 1) p += __shfl_xor(p, s, 64);
    if (l == 0) out[gw] = p;
}

// ---------------------------------------------------------------------------
extern "C" void kernel_launch(void* const* d_in, const int* in_sizes, int n_in,
                              void* d_out, int out_size, void* d_ws, size_t ws_size,
                              hipStream_t stream) {
    const float* user_x     = (const float*)d_in[0];
    const float* job_x      = (const float*)d_in[1];
    const float* user_W     = (const float*)d_in[2];
    const float* user_b     = (const float*)d_in[3];
    const float* user_gamma = (const float*)d_in[4];
    const float* user_beta  = (const float*)d_in[5];
    const float* user_mean  = (const float*)d_in[6];
    const float* user_var   = (const float*)d_in[7];
    const float* job_W      = (const float*)d_in[8];
    const float* job_b      = (const float*)d_in[9];
    const float* job_gamma  = (const float*)d_in[10];
    const float* job_beta   = (const float*)d_in[11];
    const float* job_mean   = (const float*)d_in[12];
    const float* job_var    = (const float*)d_in[13];
    const float* l1_rates_Wl = (const float*)d_in[14];
    const float* l1_rates_Wr = (const float*)d_in[15];
    const float* l1_rev_Wl   = (const float*)d_in[16];
    const float* l1_rev_Wr   = (const float*)d_in[17];
    const float* l2_rates_Wl = (const float*)d_in[18];
    const float* l2_rates_Wr = (const float*)d_in[19];
    const float* l2_rev_Wl   = (const float*)d_in[20];
    const float* l2_rev_Wr   = (const float*)d_in[21];
    const float* l1_rates_bl = (const float*)d_in[22];
    const float* l1_rev_bl   = (const float*)d_in[23];
    const float* l2_rates_bl = (const float*)d_in[24];
    const float* l2_rev_bl   = (const float*)d_in[25];
    const int* rates_src = (const int*)d_in[26];
    const int* rates_dst = (const int*)d_in[27];
    const int* label_src = (const int*)d_in[28];
    const int* label_dst = (const int*)d_in[29];

    // ---- workspace layout ----
    char* ws = (char*)d_ws;
    size_t o = 0;
    auto alloc = [&](size_t bytes) -> void* {
        void* p = ws + o;
        o = (o + bytes + 511) & ~(size_t)511;
        return p;
    };
    unsigned short* u_bf = (unsigned short*)alloc((size_t)N_USERS * HID * 2);
    unsigned short* j_bf = (unsigned short*)alloc((size_t)N_JOBS  * HID * 2);
    unsigned short* u1   = (unsigned short*)alloc((size_t)N_USERS * HID * 2);
    unsigned short* j1   = (unsigned short*)alloc((size_t)N_JOBS  * HID * 2);
    unsigned short* aggU = (unsigned short*)alloc((size_t)N_USERS * HID * 2);
    unsigned short* aggJ = (unsigned short*)alloc((size_t)N_JOBS  * HID * 2);
    float* u2f = (float*)alloc((size_t)N_USERS * HID * 4);
    float* j2f = (float*)alloc((size_t)N_JOBS  * HID * 4);
    int* vals_j = (int*)alloc((size_t)N_EDGES * 4);
    int* vals_u = (int*)alloc((size_t)N_EDGES * 4);
    unsigned* stage_j = (unsigned*)alloc((size_t)N_EDGES * 4);
    unsigned* stage_u = (unsigned*)alloc((size_t)N_EDGES * 4);
    int* off_j  = (int*)alloc((size_t)(N_JOBS + 1) * 4);
    int* off_u  = (int*)alloc((size_t)(N_USERS + 1) * 4);
    int* bcnt_j = (int*)alloc((size_t)(NBJ + 1) * 4);
    int* bcnt_u = (int*)alloc((size_t)(NBU + 1) * 4);
    int* boff_j = (int*)alloc((size_t)(NBJ + 1) * 4);
    int* boff_u = (int*)alloc((size_t)(NBU + 1) * 4);
    int* bcur_j = (int*)alloc((size_t)(NBJ + 1) * 4);
    int* bcur_u = (int*)alloc((size_t)(NBU + 1) * 4);
    unsigned short* wbf = (unsigned short*)alloc((size_t)294912 * 2);
    (void)ws_size; (void)n_in; (void)in_sizes; (void)out_size;

    const unsigned short* uWb = wbf;
    const unsigned short* jWb = wbf + 65536;
    const unsigned short* w8  = wbf + 163840;   // 8 x [128][128]

    // ---- weight conversion (once per call, tiny) ----
    cvt_weights<<<288, 256, 0, stream>>>(user_W, job_W,
        l1_rates_Wl, l1_rates_Wr, l1_rev_Wl, l1_rev_Wr,
        l2_rates_Wl, l2_rates_Wr, l2_rev_Wl, l2_rev_Wr, wbf);

    // ---- CSR build (binned, shared by both layers) ----
    hipMemsetAsync(bcnt_j, 0, (size_t)(NBJ + 1) * 4, stream);
    hipMemsetAsync(bcnt_u, 0, (size_t)(NBU + 1) * 4, stream);
    bucket_hist<<<512, 256, 0, stream>>>(rates_src, rates_dst, N_EDGES, bcnt_j, bcnt_u);
    bucket_scan<<<2, 1024, 0, stream>>>(bcnt_j, boff_j, bcur_j, bcnt_u, boff_u, bcur_u);
    csr_pass1<<<(N_EDGES + P1CHUNK - 1) / P1CHUNK, 256, 0, stream>>>(
        rates_src, rates_dst, N_EDGES, bcur_j, bcur_u, stage_j, stage_u);
    csr_pass2<<<NBJ + NBU, 256, 0, stream>>>(stage_j, boff_j, off_j, vals_j,
                                             stage_u, boff_u, off_u, vals_u);

    // ---- encoders (bf16 MFMA, 64-row tiles, prefetch) ----
    encoder_mfma<<<(N_USERS + 63) / 64, 256, 0, stream>>>(
        user_x, uWb, user_b, user_gamma, user_beta, user_mean, user_var, u_bf, N_USERS, 512);
    encoder_mfma<<<(N_JOBS + 63) / 64, 256, 0, stream>>>(
        job_x, jWb, job_b, job_gamma, job_beta, job_mean, job_var, j_bf, N_JOBS, 768);

    // ---- SAGE layer 1 (bf16 out, relu) ----
    aggregate_bf16<<<(N_JOBS + 3) / 4, 256, 0, stream>>>(u_bf, off_j, vals_j, aggJ, N_JOBS);
    sage_mfma<<<(N_JOBS + 63) / 64, 256, 0, stream>>>(
        aggJ, j_bf, w8 + 0 * 16384, w8 + 1 * 16384, l1_rates_bl, (void*)j1, N_JOBS, 1, 0);
    aggregate_bf16<<<(N_USERS + 3) / 4, 256, 0, stream>>>(j_bf, off_u, vals_u, aggU, N_USERS);
    sage_mfma<<<(N_USERS + 63) / 64, 256, 0, stream>>>(
        aggU, u_bf, w8 + 2 * 16384, w8 + 3 * 16384, l1_rev_bl, (void*)u1, N_USERS, 1, 0);

    // ---- SAGE layer 2 (fp32 out, no relu) ----
    aggregate_bf16<<<(N_JOBS + 3) / 4, 256, 0, stream>>>(u1, off_j, vals_j, aggJ, N_JOBS);
    sage_mfma<<<(N_JOBS + 63) / 64, 256, 0, stream>>>(
        aggJ, j1, w8 + 4 * 16384, w8 + 5 * 16384, l2_rates_bl, (void*)j2f, N_JOBS, 0, 1);
    aggregate_bf16<<<(N_USERS + 3) / 4, 256, 0, stream>>>(j1, off_u, vals_u, aggU, N_USERS);
    sage_mfma<<<(N_USERS + 63) / 64, 256, 0, stream>>>(
        aggU, u1, w8 + 6 * 16384, w8 + 7 * 16384, l2_rev_bl, (void*)u2f, N_USERS, 0, 1);

    // ---- link readout ----
    dot_kernel<<<(N_LABELS * 32 + 255) / 256, 256, 0, stream>>>(
        u2f, j2f, label_src, label_dst, (float*)d_out, N_LABELS);
}